// Round 9
// baseline (517.357 us; speedup 1.0000x reference)
//
#include <hip/hip_runtime.h>

#define NF 128
#define EPS 1e-5f
#define KELL 64
#define HSTRIDE 136  // ushorts per LDS row: 272 B, 16B-aligned

typedef unsigned short ushort_t;
typedef unsigned int uint_t;

using bf16x8 = __attribute__((ext_vector_type(8))) short;
using f32x4  = __attribute__((ext_vector_type(4))) float;

static __device__ inline ushort_t f2bf(float f) {
    uint_t u = __float_as_uint(f);
    return (ushort_t)((u + 0x7fffu + ((u >> 16) & 1u)) >> 16);
}
static __device__ inline float bflo(uint_t u) { return __uint_as_float(u << 16); }
static __device__ inline float bfhi(uint_t u) { return __uint_as_float(u & 0xffff0000u); }

// ---------------- GEMM core: outb(bf16) = opt_relu((h*a+c) @ W) * rowscale ----------------
// input either fp32 (Hf) or bf16 (Hb). BN-finalize fused from raw stats.

__device__ __forceinline__ void gemm_core(
    int bidx, const float* __restrict__ Hf, const ushort_t* __restrict__ Hb,
    const ushort_t* __restrict__ Wp, const float* __restrict__ stats,
    const float* __restrict__ gW, const float* __restrict__ bB, float inv_n,
    const float* __restrict__ rowscale, ushort_t* __restrict__ outb,
    int nrows, int relu, ushort_t* hs, float* acs) {
    const int tid = threadIdx.x;
    const int rb = bidx * 64;

    if (tid < 128) {
        float mean = stats[tid] * inv_n;
        float var = stats[NF + tid] * inv_n - mean * mean;
        float rstd = rsqrtf(var + EPS);
        float a = gW[tid] * rstd;
        acs[tid] = a;
        acs[NF + tid] = bB[tid] - mean * a;
    }
    __syncthreads();

    if (Hf) {
        const float4* ac4 = (const float4*)acs;
#pragma unroll
        for (int p = 0; p < 8; ++p) {
            int idx = p * 256 + tid;         // 0..2047 float4s
            int r = idx >> 5, k4 = idx & 31;
            int gr = rb + r;
            float4 v = (gr < nrows) ? *(const float4*)&Hf[(size_t)gr * NF + k4 * 4]
                                    : make_float4(0.f, 0.f, 0.f, 0.f);
            float4 a4 = ac4[k4], c4 = ac4[32 + k4];
            ushort_t o[4];
            o[0] = f2bf(fmaf(v.x, a4.x, c4.x));
            o[1] = f2bf(fmaf(v.y, a4.y, c4.y));
            o[2] = f2bf(fmaf(v.z, a4.z, c4.z));
            o[3] = f2bf(fmaf(v.w, a4.w, c4.w));
            *(uint2*)&hs[r * HSTRIDE + k4 * 4] = *(uint2*)o;
        }
    } else {
#pragma unroll
        for (int p = 0; p < 4; ++p) {
            int idx = p * 256 + tid;         // 0..1023 uint4s (8 bf16 each)
            int r = idx >> 4, g8 = idx & 15;
            int gr = rb + r;
            uint4 u = (gr < nrows) ? *(const uint4*)&Hb[(size_t)gr * NF + g8 * 8]
                                   : make_uint4(0, 0, 0, 0);
            int c0 = g8 * 8;
            ushort_t o[8];
            o[0] = f2bf(fmaf(bflo(u.x), acs[c0],     acs[NF + c0]));
            o[1] = f2bf(fmaf(bfhi(u.x), acs[c0 + 1], acs[NF + c0 + 1]));
            o[2] = f2bf(fmaf(bflo(u.y), acs[c0 + 2], acs[NF + c0 + 2]));
            o[3] = f2bf(fmaf(bfhi(u.y), acs[c0 + 3], acs[NF + c0 + 3]));
            o[4] = f2bf(fmaf(bflo(u.z), acs[c0 + 4], acs[NF + c0 + 4]));
            o[5] = f2bf(fmaf(bfhi(u.z), acs[c0 + 5], acs[NF + c0 + 5]));
            o[6] = f2bf(fmaf(bflo(u.w), acs[c0 + 6], acs[NF + c0 + 6]));
            o[7] = f2bf(fmaf(bfhi(u.w), acs[c0 + 7], acs[NF + c0 + 7]));
            *(uint4*)&hs[r * HSTRIDE + c0] = *(uint4*)o;
        }
    }
    __syncthreads();

    const int wave = tid >> 6, lane = tid & 63;
    const int m = lane & 15, q = lane >> 4;
    const ushort_t* arow = &hs[(wave * 16 + m) * HSTRIDE];

    f32x4 acc[8];
#pragma unroll
    for (int ct = 0; ct < 8; ++ct) acc[ct] = (f32x4){0.f, 0.f, 0.f, 0.f};

#pragma unroll
    for (int kc = 0; kc < 4; ++kc) {
        bf16x8 af = *(const bf16x8*)&arow[kc * 32 + q * 8];
        const ushort_t* wp = Wp + kc * 4096 + lane * 8;
#pragma unroll
        for (int ct = 0; ct < 8; ++ct) {
            bf16x8 bfr = *(const bf16x8*)&wp[ct * 512];
            acc[ct] = __builtin_amdgcn_mfma_f32_16x16x32_bf16(af, bfr, acc[ct], 0, 0, 0);
        }
    }

    __syncthreads();  // hs reads done; reuse for output transpose
#pragma unroll
    for (int r = 0; r < 4; ++r) {
        int row = wave * 16 + q * 4 + r;
        int grow = rb + row;
        float rs = rowscale ? ((grow < nrows) ? rowscale[grow] : 0.f) : 1.0f;
#pragma unroll
        for (int ct = 0; ct < 8; ++ct) {
            float v = acc[ct][r];
            if (relu) v = fmaxf(v, 0.f);
            hs[row * HSTRIDE + ct * 16 + m] = f2bf(v * rs);
        }
    }
    __syncthreads();
    {
        int row = tid >> 2, p = tid & 3;  // 4 threads/row, 32 ushorts each
        int grow = rb + row;
        if (grow < nrows) {
            const ushort_t* src = &hs[row * HSTRIDE + p * 32];
            ushort_t* dst = &outb[(size_t)grow * NF + p * 32];
#pragma unroll
            for (int s4 = 0; s4 < 4; ++s4)
                *(uint4*)&dst[s4 * 8] = *(const uint4*)&src[s4 * 8];
        }
    }
}

// ---------------- mega1: ELL fill + bn_stats(x) + weight pack (independent) ----------------

__global__ void mega1(const int* __restrict__ ei, int* __restrict__ scnt,
                      int* __restrict__ dcnt, ushort_t* __restrict__ colx, int E,
                      const float* __restrict__ x, float* __restrict__ st_x, int n,
                      const float* __restrict__ W0, const float* __restrict__ W123,
                      ushort_t* __restrict__ Wp, int nbe) {
    int b = blockIdx.x;
    if (b < nbe) {
        int e = b * 256 + threadIdx.x;
        if (e < E) {
            int s = ei[e], d = ei[E + e];
            atomicAdd(&scnt[s], 1);
            int pos = atomicAdd(&dcnt[d], 1);
            if (pos < KELL - 1) colx[d * KELL + pos] = (ushort_t)s;
        }
    } else if (b < nbe + 512) {
        int sb = b - nbe;
        int j = threadIdx.x & 127;
        int half = threadIdx.x >> 7;
        float s = 0.f, q = 0.f;
        for (int r = sb * 2 + half; r < n; r += 1024) {
            float v = x[(size_t)r * NF + j];
            s += v;
            q += v * v;
        }
        __shared__ float ls[256], lq[256];
        ls[threadIdx.x] = s; lq[threadIdx.x] = q;
        __syncthreads();
        if (threadIdx.x < 128) {
            atomicAdd(&st_x[j], ls[threadIdx.x] + ls[threadIdx.x + 128]);
            atomicAdd(&st_x[NF + j], lq[threadIdx.x] + lq[threadIdx.x + 128]);
        }
    } else {
        int gidx = (b - nbe - 512) * 256 + threadIdx.x;  // 0..8191
        int mat = gidx >> 11, idx = gidx & 2047;
        const float* W = (mat == 0) ? W0 : (W123 + (size_t)(mat - 1) * NF * NF);
        int lane = idx & 63, ct = (idx >> 6) & 7, kc = idx >> 9;
        int m = lane & 15, q = lane >> 4;
        ushort_t o[8];
#pragma unroll
        for (int j = 0; j < 8; ++j)
            o[j] = f2bf(W[(kc * 32 + q * 8 + j) * NF + ct * 16 + m]);
        *(uint4*)&Wp[(size_t)gidx * 8] = *(uint4*)o;
    }
}

// ---------------- mega2: feat GEMM + ELL finish (independent) ----------------

__launch_bounds__(256)
__global__ void mega2(const float* __restrict__ x, const ushort_t* __restrict__ Wp,
                      const float* __restrict__ st_x, const float* __restrict__ gW,
                      const float* __restrict__ bB, float inv_n, ushort_t* __restrict__ A,
                      const int* __restrict__ scnt, const int* __restrict__ dcnt,
                      float* __restrict__ dinv, ushort_t* __restrict__ colx,
                      ushort_t* __restrict__ BbSent, int n, int nbg) {
    __shared__ ushort_t hs[64 * HSTRIDE];
    __shared__ float acs[256];
    int b = blockIdx.x;
    if (b < nbg) {
        gemm_core(b, x, nullptr, Wp, st_x, gW, bB, inv_n, nullptr, A, n, 1, hs, acs);
    } else {
        int i = (b - nbg) * 256 + threadIdx.x;
        if (i < n) {
            dinv[i] = rsqrtf((float)scnt[i] + 1.0f);
            int dc = min(dcnt[i], KELL - 1);
            ushort_t* row = colx + i * KELL;
            row[dc] = (ushort_t)i;            // self loop
            int len = (dc + 16) & ~15;        // pad to 16
            for (int q = dc + 1; q < len; ++q) row[q] = (ushort_t)n;
        }
        if (b == nbg && threadIdx.x < 64)
            ((uint_t*)BbSent)[threadIdx.x] = 0;  // zero sentinel bf16 row
    }
}

// ---------------- conv GEMM ----------------

__launch_bounds__(256)
__global__ void gemm_conv(const ushort_t* __restrict__ A, const ushort_t* __restrict__ Wp,
                          const float* __restrict__ stats, const float* __restrict__ gW,
                          const float* __restrict__ bB, float inv_n,
                          const float* __restrict__ dinv, ushort_t* __restrict__ Bb, int n) {
    __shared__ ushort_t hs[64 * HSTRIDE];
    __shared__ float acs[256];
    gemm_core(blockIdx.x, nullptr, A, Wp, stats, gW, bB, inv_n, dinv, Bb, n, 0, hs, acs);
}

// ---------------- bn stats over bf16 rows ----------------

__global__ void bn_stats_bf(const ushort_t* __restrict__ h, float* __restrict__ stats, int n) {
    int cp = threadIdx.x & 63;   // col pair
    int rg = threadIdx.x >> 6;   // 0..3
    float s0 = 0.f, q0 = 0.f, s1 = 0.f, q1 = 0.f;
    for (int r = blockIdx.x * 4 + rg; r < n; r += gridDim.x * 4) {
        uint_t u = *(const uint_t*)&h[(size_t)r * NF + cp * 2];
        float v0 = bflo(u), v1 = bfhi(u);
        s0 += v0; q0 += v0 * v0;
        s1 += v1; q1 += v1 * v1;
    }
    __shared__ float red[4][256];
    red[0][threadIdx.x] = s0; red[1][threadIdx.x] = q0;
    red[2][threadIdx.x] = s1; red[3][threadIdx.x] = q1;
    __syncthreads();
    if (threadIdx.x < 64) {
        int c = threadIdx.x;
        float S0 = 0.f, Q0 = 0.f, S1 = 0.f, Q1 = 0.f;
#pragma unroll
        for (int g = 0; g < 4; ++g) {
            S0 += red[0][g * 64 + c]; Q0 += red[1][g * 64 + c];
            S1 += red[2][g * 64 + c]; Q1 += red[3][g * 64 + c];
        }
        atomicAdd(&stats[c * 2], S0);
        atomicAdd(&stats[c * 2 + 1], S1);
        atomicAdd(&stats[NF + c * 2], Q0);
        atomicAdd(&stats[NF + c * 2 + 1], Q1);
    }
}

// fp32 stats (y2 path)
__global__ void bn_stats(const float* __restrict__ h, float* __restrict__ stats, int n) {
    int j = threadIdx.x & 127;
    int half = threadIdx.x >> 7;
    float s = 0.f, q = 0.f;
    for (int r = blockIdx.x * 2 + half; r < n; r += gridDim.x * 2) {
        float v = h[r * NF + j];
        s += v;
        q += v * v;
    }
    __shared__ float ls[256], lq[256];
    ls[threadIdx.x] = s; lq[threadIdx.x] = q;
    __syncthreads();
    if (threadIdx.x < 128) {
        atomicAdd(&stats[j], ls[threadIdx.x] + ls[threadIdx.x + 128]);
        atomicAdd(&stats[NF + j], lq[threadIdx.x] + lq[threadIdx.x + 128]);
    }
}

// ---------------- GCN aggregation (ELL, ushort cols, MLP=16, bf16 in/out) ----------------

#define CVT2(u, a, b) { a = __uint_as_float((u) << 16); b = __uint_as_float((u) & 0xffff0000u); }
#define ACC8(q) { float p0, p1, p2, p3, p4, p5, p6, p7;                          \
    CVT2(q.x, p0, p1) CVT2(q.y, p2, p3) CVT2(q.z, p4, p5) CVT2(q.w, p6, p7)      \
    acc[0] += p0; acc[1] += p1; acc[2] += p2; acc[3] += p3;                      \
    acc[4] += p4; acc[5] += p5; acc[6] += p6; acc[7] += p7; }

__launch_bounds__(256)
__global__ void k_aggregate_bf(const ushort_t* __restrict__ xwb, const int* __restrict__ dcnt,
                               const ushort_t* __restrict__ colx, const float* __restrict__ dinv,
                               const float* __restrict__ bias, ushort_t* __restrict__ out, int n) {
    int node = blockIdx.x * 16 + (threadIdx.x >> 4);
    int lane = threadIdx.x & 15;
    if (node >= n) return;
    const uint4* __restrict__ xq = (const uint4*)xwb;
    float acc[8];
#pragma unroll
    for (int j = 0; j < 8; ++j) acc[j] = 0.f;
    int dc = min(dcnt[node], KELL - 1);
    int len = (dc + 16) & ~15;
    int e0 = node * KELL;
    for (int e = e0; e < e0 + len; e += 16) {
        uint4 ia = *(const uint4*)&colx[e];
        uint4 ib = *(const uint4*)&colx[e + 8];
        int i0 = ia.x & 0xffff, i1 = ia.x >> 16;
        int i2 = ia.y & 0xffff, i3 = ia.y >> 16;
        int i4 = ia.z & 0xffff, i5 = ia.z >> 16;
        int i6 = ia.w & 0xffff, i7 = ia.w >> 16;
        int i8 = ib.x & 0xffff, i9 = ib.x >> 16;
        int iA = ib.y & 0xffff, iB = ib.y >> 16;
        int iC = ib.z & 0xffff, iD = ib.z >> 16;
        int iE = ib.w & 0xffff, iF = ib.w >> 16;
        uint4 q0 = xq[(size_t)i0 * 16 + lane];
        uint4 q1 = xq[(size_t)i1 * 16 + lane];
        uint4 q2 = xq[(size_t)i2 * 16 + lane];
        uint4 q3 = xq[(size_t)i3 * 16 + lane];
        uint4 q4 = xq[(size_t)i4 * 16 + lane];
        uint4 q5 = xq[(size_t)i5 * 16 + lane];
        uint4 q6 = xq[(size_t)i6 * 16 + lane];
        uint4 q7 = xq[(size_t)i7 * 16 + lane];
        uint4 q8 = xq[(size_t)i8 * 16 + lane];
        uint4 q9 = xq[(size_t)i9 * 16 + lane];
        uint4 qA = xq[(size_t)iA * 16 + lane];
        uint4 qB = xq[(size_t)iB * 16 + lane];
        uint4 qC = xq[(size_t)iC * 16 + lane];
        uint4 qD = xq[(size_t)iD * 16 + lane];
        uint4 qE = xq[(size_t)iE * 16 + lane];
        uint4 qF = xq[(size_t)iF * 16 + lane];
        ACC8(q0) ACC8(q1) ACC8(q2) ACC8(q3)
        ACC8(q4) ACC8(q5) ACC8(q6) ACC8(q7)
        ACC8(q8) ACC8(q9) ACC8(qA) ACC8(qB)
        ACC8(qC) ACC8(qD) ACC8(qE) ACC8(qF)
    }
    float di = dinv[node];
    float4 b0 = *(const float4*)&bias[lane * 8];
    float4 b1 = *(const float4*)&bias[lane * 8 + 4];
    ushort_t o8[8];
    o8[0] = f2bf(fmaxf(fmaf(di, acc[0], b0.x), 0.f));
    o8[1] = f2bf(fmaxf(fmaf(di, acc[1], b0.y), 0.f));
    o8[2] = f2bf(fmaxf(fmaf(di, acc[2], b0.z), 0.f));
    o8[3] = f2bf(fmaxf(fmaf(di, acc[3], b0.w), 0.f));
    o8[4] = f2bf(fmaxf(fmaf(di, acc[4], b1.x), 0.f));
    o8[5] = f2bf(fmaxf(fmaf(di, acc[5], b1.y), 0.f));
    o8[6] = f2bf(fmaxf(fmaf(di, acc[6], b1.z), 0.f));
    o8[7] = f2bf(fmaxf(fmaf(di, acc[7], b1.w), 0.f));
    *(uint4*)&out[(size_t)node * NF + lane * 8] = *(uint4*)o8;
}

// ---------------- pooling (sorted batch, bf16 in, stats fused) ----------------

__global__ void k_pool(const ushort_t* __restrict__ h, const int* __restrict__ batch,
                       float* __restrict__ pooled, float* __restrict__ stats, int n) {
    int g = blockIdx.x;
    int t = threadIdx.x;  // 64 threads, col pair 2t,2t+1
    int lo = 0, hi = n;
    while (lo < hi) { int m = (lo + hi) >> 1; if (batch[m] < g) lo = m + 1; else hi = m; }
    int start = lo;
    lo = start; hi = n;
    while (lo < hi) { int m = (lo + hi) >> 1; if (batch[m] < g + 1) lo = m + 1; else hi = m; }
    int end = lo;
    float a0 = 0.f, a1 = 0.f, b0 = 0.f, b1 = 0.f;
    int r = start;
    for (; r + 2 <= end; r += 2) {
        uint_t u0 = *(const uint_t*)&h[(size_t)r * NF + t * 2];
        uint_t u1 = *(const uint_t*)&h[(size_t)(r + 1) * NF + t * 2];
        a0 += bflo(u0); a1 += bfhi(u0);
        b0 += bflo(u1); b1 += bfhi(u1);
    }
    if (r < end) {
        uint_t u0 = *(const uint_t*)&h[(size_t)r * NF + t * 2];
        a0 += bflo(u0); a1 += bfhi(u0);
    }
    float v0 = a0 + b0, v1 = a1 + b1;
    pooled[g * NF + t * 2] = v0;
    pooled[g * NF + t * 2 + 1] = v1;
    atomicAdd(&stats[t * 2], v0);
    atomicAdd(&stats[t * 2 + 1], v1);
    atomicAdd(&stats[NF + t * 2], v0 * v0);
    atomicAdd(&stats[NF + t * 2 + 1], v1 * v1);
}

// ---------------- fc vector GEMM (fp32, fused BN-finalize) ----------------

__launch_bounds__(256)
__global__ void gemm_bn(const float* __restrict__ Hh, const float* __restrict__ W,
                        const float* __restrict__ stats, const float* __restrict__ gW,
                        const float* __restrict__ bB, float inv_n,
                        const float* __restrict__ bias,
                        float* __restrict__ out, int nrows, int relu) {
    __shared__ float hsb[64][133];
    __shared__ float acs[256];
    const int tid = threadIdx.x;
    const int tx = tid & 15;
    const int ty = tid >> 4;
    const int rb = blockIdx.x * 64;

    if (tid < 128) {
        float mean = stats[tid] * inv_n;
        float var = stats[NF + tid] * inv_n - mean * mean;
        float rstd = rsqrtf(var + EPS);
        float a = gW[tid] * rstd;
        acs[tid] = a;
        acs[NF + tid] = bB[tid] - mean * a;
    }
    __syncthreads();

#pragma unroll 8
    for (int p = 0; p < 32; ++p) {
        int idx = p * 256 + tid;
        int r = idx >> 7, k = idx & 127;
        int gr = rb + r;
        float v = (gr < nrows) ? Hh[(size_t)gr * NF + k] : 0.f;
        hsb[r][k] = fmaf(v, acs[k], acs[NF + k]);
    }
    __syncthreads();

    float acc[4][8];
#pragma unroll
    for (int i = 0; i < 4; ++i)
#pragma unroll
        for (int j = 0; j < 8; ++j) acc[i][j] = 0.f;

    const int c0 = tx * 4, c1 = 64 + tx * 4;
#pragma unroll 4
    for (int k = 0; k < 128; ++k) {
        const float4 b0 = *(const float4*)&W[k * NF + c0];
        const float4 b1 = *(const float4*)&W[k * NF + c1];
#pragma unroll
        for (int i = 0; i < 4; ++i) {
            float a = hsb[ty * 4 + i][k];
            acc[i][0] = fmaf(a, b0.x, acc[i][0]);
            acc[i][1] = fmaf(a, b0.y, acc[i][1]);
            acc[i][2] = fmaf(a, b0.z, acc[i][2]);
            acc[i][3] = fmaf(a, b0.w, acc[i][3]);
            acc[i][4] = fmaf(a, b1.x, acc[i][4]);
            acc[i][5] = fmaf(a, b1.y, acc[i][5]);
            acc[i][6] = fmaf(a, b1.z, acc[i][6]);
            acc[i][7] = fmaf(a, b1.w, acc[i][7]);
        }
    }

#pragma unroll
    for (int i = 0; i < 4; ++i) {
        int gr = rb + ty * 4 + i;
        if (gr < nrows) {
            float o[8];
#pragma unroll
            for (int j = 0; j < 8; ++j) {
                int c = (j < 4) ? (c0 + j) : (c1 + j - 4);
                float v = acc[i][j] + (bias ? bias[c] : 0.f);
                o[j] = relu ? fmaxf(v, 0.f) : v;
            }
            *(float4*)&out[(size_t)gr * NF + c0] = make_float4(o[0], o[1], o[2], o[3]);
            *(float4*)&out[(size_t)gr * NF + c1] = make_float4(o[4], o[5], o[6], o[7]);
        }
    }
}

// ---------------- classifier + log_softmax (fused BN-finalize) ----------------

__global__ void k_cls(const float* __restrict__ h, const float* __restrict__ stats,
                      const float* __restrict__ gW, const float* __restrict__ bB,
                      float inv_n, const float* __restrict__ Wc,
                      const float* __restrict__ bc, float* __restrict__ out, int C_) {
    __shared__ float hr[128];
    __shared__ float lg[16];
    __shared__ float lse_s;
    int r = blockIdx.x, t = threadIdx.x;  // 64 threads
#pragma unroll
    for (int half = 0; half < 2; ++half) {
        int j = t + half * 64;
        float mean = stats[j] * inv_n;
        float var = stats[NF + j] * inv_n - mean * mean;
        float rstd = rsqrtf(var + EPS);
        float a = gW[j] * rstd;
        float c = bB[j] - mean * a;
        hr[j] = fmaf(h[r * NF + j], a, c);
    }
    __syncthreads();
    if (t < C_) {
        float s = bc[t];
        for (int k = 0; k < 128; ++k) s = fmaf(hr[k], Wc[k * C_ + t], s);
        lg[t] = s;
    }
    __syncthreads();
    if (t == 0) {
        float m = -1e30f;
        for (int c = 0; c < C_; ++c) m = fmaxf(m, lg[c]);
        float se = 0.f;
        for (int c = 0; c < C_; ++c) se += expf(lg[c] - m);
        lse_s = m + logf(se);
    }
    __syncthreads();
    if (t < C_) out[r * C_ + t] = lg[t] - lse_s;
}

// ---------------- launch ----------------

extern "C" void kernel_launch(void* const* d_in, const int* in_sizes, int n_in,
                              void* d_out, int out_size, void* d_ws, size_t ws_size,
                              hipStream_t stream) {
    const float* x          = (const float*)d_in[0];
    const int*   ei         = (const int*)d_in[1];
    const int*   batch      = (const int*)d_in[2];
    const float* bn_feat_g  = (const float*)d_in[3];
    const float* bn_feat_b  = (const float*)d_in[4];
    const float* W_feat     = (const float*)d_in[5];
    const float* bns_conv_g = (const float*)d_in[6];
    const float* bns_conv_b = (const float*)d_in[7];
    const float* W_conv     = (const float*)d_in[8];
    const float* b_conv     = (const float*)d_in[9];
    const float* bn_fc_g    = (const float*)d_in[10];
    const float* bn_fc_b    = (const float*)d_in[11];
    const float* W_lin      = (const float*)d_in[12];
    const float* b_lin      = (const float*)d_in[13];
    const float* bn_hid_g   = (const float*)d_in[14];
    const float* bn_hid_b   = (const float*)d_in[15];
    const float* W_cls      = (const float*)d_in[16];
    const float* b_cls      = (const float*)d_in[17];
    float* outp = (float*)d_out;

    const int N_ = in_sizes[2];
    const int E_ = in_sizes[1] / 2;
    const int C_ = 10;
    const int G_ = out_size / C_;

    char* wsp = (char*)d_ws;
    auto alloc = [&](size_t bytes) {
        void* p = (void*)wsp;
        wsp += (bytes + 255) & ~(size_t)255;
        return p;
    };
    int*      cnts   = (int*)alloc((size_t)2 * N_ * 4);      // scnt | dcnt (zeroed w/ statsA)
    float*    statsA = (float*)alloc(6 * 256 * 4);
    ushort_t* A      = (ushort_t*)alloc((size_t)N_ * NF * 2);        // bf16 activations
    ushort_t* Bb     = (ushort_t*)alloc((size_t)(N_ + 1) * NF * 2);  // bf16 xw + zero row
    float*    dinv   = (float*)alloc((size_t)N_ * 4);
    ushort_t* colx   = (ushort_t*)alloc((size_t)N_ * KELL * 2);
    ushort_t* Wp     = (ushort_t*)alloc((size_t)4 * NF * NF * 2);
    float*    pooled = (float*)alloc((size_t)G_ * NF * 4);
    float*    y2     = (float*)alloc((size_t)G_ * NF * 4);

    int* scnt = cnts;
    int* dcnt = cnts + N_;
    float* st_x  = statsA;
    float* st_f  = statsA + 256;
    float* st_a1 = statsA + 512;
    float* st_a2 = statsA + 768;
    float* st_pl = statsA + 1024;
    float* st_y2 = statsA + 1280;

    int nb_n = (N_ + 255) / 256;
    int nb_e = (E_ + 255) / 256;
    int nb_g = (N_ + 63) / 64;

    size_t cnt_rounded = (((size_t)2 * N_ * 4) + 255) & ~(size_t)255;
    hipMemsetAsync(cnts, 0, cnt_rounded + 6 * 256 * 4, stream);

    // mega1: ELL fill + bn_stats(x) + pack all 4 W
    mega1<<<nb_e + 512 + 32, 256, 0, stream>>>(ei, scnt, dcnt, colx, E_,
                                               x, st_x, N_, W_feat, W_conv, Wp, nb_e);

    // mega2: feat GEMM (x -> A bf16) + ELL finish (+ Bb sentinel zero)
    mega2<<<nb_g + nb_n, 256, 0, stream>>>(x, Wp, st_x, bn_feat_g, bn_feat_b, 1.0f / N_,
                                           A, scnt, dcnt, dinv, colx,
                                           Bb + (size_t)N_ * NF, N_, nb_g);
    bn_stats_bf<<<512, 256, 0, stream>>>(A, st_f, N_);

    // conv layers
    float* st_in[3] = {st_f, st_a1, st_a2};
    float* st_out[3] = {st_a1, st_a2, nullptr};
    for (int l = 0; l < 3; ++l) {
        gemm_conv<<<nb_g, 256, 0, stream>>>(A, Wp + (size_t)(l + 1) * NF * NF,
                                            st_in[l], bns_conv_g + l * NF, bns_conv_b + l * NF,
                                            1.0f / N_, dinv, Bb, N_);
        k_aggregate_bf<<<(N_ + 15) / 16, 256, 0, stream>>>(Bb, dcnt, colx, dinv,
                                                           b_conv + l * NF, A, N_);
        if (st_out[l])
            bn_stats_bf<<<512, 256, 0, stream>>>(A, st_out[l], N_);
    }

    // pool (bf16 in, stats fused)
    k_pool<<<G_, 64, 0, stream>>>(A, batch, pooled, st_pl, N_);

    // fc (fp32 vector path, fused finalize)
    gemm_bn<<<(G_ + 63) / 64, 256, 0, stream>>>(pooled, W_lin, st_pl, bn_fc_g, bn_fc_b,
                                                1.0f / G_, b_lin, y2, G_, 1);
    bn_stats<<<128, 256, 0, stream>>>(y2, st_y2, G_);

    // classifier (fused finalize)
    k_cls<<<G_, 64, 0, stream>>>(y2, st_y2, bn_hid_g, bn_hid_b, 1.0f / G_,
                                 W_cls, b_cls, outp, C_);
}